// Round 1
// baseline (276.075 us; speedup 1.0000x reference)
//
#include <hip/hip_runtime.h>

#define HH 224
#define WW 224
#define HWSZ (HH * WW)   // 50176
#define BB 8
#define CC 64
#define NP 8
#define TL 128           // l-tile for gather kernel (50176 / 128 = 392 exact)
#define LT 64            // l-tile for transpose kernel (50176 / 64 = 784 exact)

// ---------------------------------------------------------------------------
// Kernel 1: transpose img [B][C][HW] -> img_t [B][HW][C]
// Both global read and write are float4-coalesced; LDS 2-way max conflicts.
// ---------------------------------------------------------------------------
__global__ __launch_bounds__(256) void transpose_kernel(const float* __restrict__ img,
                                                        float* __restrict__ img_t) {
    __shared__ float lds[CC][LT + 1];
    const int b   = blockIdx.y;
    const int l0  = blockIdx.x * LT;
    const int tid = threadIdx.x;

    const float* src = img + (size_t)b * CC * HWSZ;
    #pragma unroll
    for (int it = 0; it < 4; ++it) {
        const int c = (tid >> 4) + it * 16;   // 0..63
        const int m = tid & 15;               // float4 slot along l
        float4 v = *reinterpret_cast<const float4*>(src + (size_t)c * HWSZ + l0 + 4 * m);
        lds[c][4 * m + 0] = v.x;
        lds[c][4 * m + 1] = v.y;
        lds[c][4 * m + 2] = v.z;
        lds[c][4 * m + 3] = v.w;
    }
    __syncthreads();

    float* dst = img_t + (size_t)b * HWSZ * CC;
    #pragma unroll
    for (int it = 0; it < 4; ++it) {
        const int l  = (tid >> 4) + it * 16;  // 0..63
        const int c0 = (tid & 15) * 4;        // 0,4,...,60
        float4 v;
        v.x = lds[c0 + 0][l];
        v.y = lds[c0 + 1][l];
        v.z = lds[c0 + 2][l];
        v.w = lds[c0 + 3][l];
        *reinterpret_cast<float4*>(dst + (size_t)(l0 + l) * CC + c0) = v;
    }
}

// ---------------------------------------------------------------------------
// Kernel 2: gather. Block = (l-tile, p, b). Reads img_t rows (256 B
// contiguous per pixel) coalesced into a swizzled LDS tile [C][TL], then
// writes out[b][p*C+c][l0..l0+TL) as float4 (fully coalesced store stream).
// Swizzle: element (c,l) lives at tile[c][(((l>>2) ^ (c>>2)) << 2) + (l&3)].
// ---------------------------------------------------------------------------
__global__ __launch_bounds__(256) void gather_kernel(const float* __restrict__ img_t,
                                                     const int* __restrict__ paths,
                                                     float* __restrict__ out) {
    __shared__ float tile[CC][TL];    // 32 KB, XOR-swizzled on 16B groups
    __shared__ int sidx[TL];

    const int tid = threadIdx.x;
    const int tI  = blockIdx.x;       // l-tile index
    const int p   = blockIdx.y;
    const int b   = blockIdx.z;
    const int l0  = tI * TL;

    if (tid < TL) {
        int2 hw2 = reinterpret_cast<const int2*>(paths)[(size_t)p * HWSZ + l0 + tid];
        sidx[tid] = hw2.x * WW + hw2.y;
    }
    __syncthreads();

    const float* src = img_t + (size_t)b * HWSZ * CC;

    // Gather phase: 8 iters x 256 threads x float4 = 8192 floats = 64x128 tile.
    // slot -> l = slot>>4 (16 c-slots per l), c0 = (slot&15)*4.
    #pragma unroll
    for (int it = 0; it < 8; ++it) {
        const int slot = it * 256 + tid;
        const int l    = slot >> 4;           // 0..127
        const int u    = slot & 15;           // c-group
        const int c0   = u << 2;              // 0,4,...,60
        float4 v = *reinterpret_cast<const float4*>(src + (size_t)sidx[l] * CC + c0);
        const int gs = (((l >> 2) ^ u) << 2) + (l & 3);   // swizzled column
        tile[c0 + 0][gs] = v.x;
        tile[c0 + 1][gs] = v.y;
        tile[c0 + 2][gs] = v.z;
        tile[c0 + 3][gs] = v.w;
    }
    __syncthreads();

    // Write phase: c = it*8 + tid/32, s = tid&31 -> l = 4s..4s+3, float4 out.
    float* dst = out + ((size_t)b * (NP * CC) + (size_t)p * CC) * HWSZ + l0;
    #pragma unroll
    for (int it = 0; it < 8; ++it) {
        const int c = it * 8 + (tid >> 5);    // 0..63
        const int s = tid & 31;               // l-group
        const int g = (s ^ (c >> 2)) << 2;    // swizzled 16B group
        float4 v;
        v.x = tile[c][g + 0];
        v.y = tile[c][g + 1];
        v.z = tile[c][g + 2];
        v.w = tile[c][g + 3];
        *reinterpret_cast<float4*>(dst + (size_t)c * HWSZ + 4 * s) = v;
    }
}

// ---------------------------------------------------------------------------
// Fallback (only if ws too small): direct gather, lanes along l, loop c.
// ---------------------------------------------------------------------------
__global__ __launch_bounds__(256) void naive_gather(const float* __restrict__ img,
                                                    const int* __restrict__ paths,
                                                    float* __restrict__ out) {
    const int l = blockIdx.x * 256 + threadIdx.x;
    const int p = blockIdx.y;
    const int b = blockIdx.z;
    int2 hw2 = reinterpret_cast<const int2*>(paths)[(size_t)p * HWSZ + l];
    const int idx = hw2.x * WW + hw2.y;
    const float* src = img + (size_t)b * CC * HWSZ;
    float* dst = out + ((size_t)b * NP + p) * (size_t)(CC * HWSZ) + l;
    #pragma unroll 4
    for (int c = 0; c < CC; ++c) {
        dst[(size_t)c * HWSZ] = src[(size_t)c * HWSZ + idx];
    }
}

extern "C" void kernel_launch(void* const* d_in, const int* in_sizes, int n_in,
                              void* d_out, int out_size, void* d_ws, size_t ws_size,
                              hipStream_t stream) {
    const float* img   = (const float*)d_in[0];
    const int*   paths = (const int*)d_in[1];
    float*       out   = (float*)d_out;

    const size_t need = (size_t)BB * HWSZ * CC * sizeof(float);  // 102.8 MB
    if (ws_size >= need) {
        float* img_t = (float*)d_ws;
        transpose_kernel<<<dim3(HWSZ / LT, BB), 256, 0, stream>>>(img, img_t);
        gather_kernel<<<dim3(HWSZ / TL, NP, BB), 256, 0, stream>>>(img_t, paths, out);
    } else {
        naive_gather<<<dim3(HWSZ / 256, NP, BB), 256, 0, stream>>>(img, paths, out);
    }
}

// Round 2
// 248.017 us; speedup vs baseline: 1.1131x; 1.1131x over previous
//
#include <hip/hip_runtime.h>

typedef float f32x4 __attribute__((ext_vector_type(4)));

#define HH 224
#define WW 224
#define HWSZ (HH * WW)   // 50176
#define BB 8
#define CC 64
#define NP 8
#define TL 128           // l-tile for gather kernel (50176 / 128 = 392 exact)
#define LT 64            // l-tile for transpose kernel (50176 / 64 = 784 exact)

// ---------------------------------------------------------------------------
// Kernel 1: transpose img [B][C][HW] -> img_t [B][HW][C]
// Both global read and write are float4-coalesced; LDS 2-way max (free).
// ---------------------------------------------------------------------------
__global__ __launch_bounds__(256) void transpose_kernel(const float* __restrict__ img,
                                                        float* __restrict__ img_t) {
    __shared__ float lds[CC][LT + 1];
    const int b   = blockIdx.y;
    const int l0  = blockIdx.x * LT;
    const int tid = threadIdx.x;

    const float* src = img + (size_t)b * CC * HWSZ;
    #pragma unroll
    for (int it = 0; it < 4; ++it) {
        const int c = (tid >> 4) + it * 16;   // 0..63
        const int m = tid & 15;               // float4 slot along l
        float4 v = *reinterpret_cast<const float4*>(src + (size_t)c * HWSZ + l0 + 4 * m);
        lds[c][4 * m + 0] = v.x;
        lds[c][4 * m + 1] = v.y;
        lds[c][4 * m + 2] = v.z;
        lds[c][4 * m + 3] = v.w;
    }
    __syncthreads();

    float* dst = img_t + (size_t)b * HWSZ * CC;
    #pragma unroll
    for (int it = 0; it < 4; ++it) {
        const int l  = (tid >> 4) + it * 16;  // 0..63
        const int c0 = (tid & 15) * 4;        // 0,4,...,60
        float4 v;
        v.x = lds[c0 + 0][l];
        v.y = lds[c0 + 1][l];
        v.z = lds[c0 + 2][l];
        v.w = lds[c0 + 3][l];
        *reinterpret_cast<float4*>(dst + (size_t)(l0 + l) * CC + c0) = v;
    }
}

// ---------------------------------------------------------------------------
// Kernel 2: gather. Block = (l-tile, p, b), 512 threads (8 waves -> with
// 32.5 KB LDS: 4 blocks/CU = 32 waves/CU, 100% occupancy).
// Phase 1: coalesced 256 B pixel-row reads from img_t into XOR-swizzled LDS
//          tile (scalar stores, 2-way = free).
// Phase 2: ds_read_b128 (swizzle keeps 16 B groups contiguous; 8 words/bank
//          per wave = transfer-floor, conflict-free) + nontemporal float4
//          stores of the 822 MB output stream (keep L2/L3 warm for img_t).
// Swizzle: element (c,l) lives at tile[c][(((l>>2) ^ (c>>2)) << 2) + (l&3)].
// ---------------------------------------------------------------------------
__global__ __launch_bounds__(512) void gather_kernel(const float* __restrict__ img_t,
                                                     const int* __restrict__ paths,
                                                     float* __restrict__ out) {
    __shared__ float tile[CC][TL];    // 32 KB, XOR-swizzled on 16B groups
    __shared__ int sidx[TL];

    const int tid = threadIdx.x;
    const int l0  = blockIdx.x * TL;
    const int p   = blockIdx.y;
    const int b   = blockIdx.z;

    if (tid < TL) {
        int2 hw2 = reinterpret_cast<const int2*>(paths)[(size_t)p * HWSZ + l0 + tid];
        sidx[tid] = hw2.x * WW + hw2.y;
    }
    __syncthreads();

    const float* src = img_t + (size_t)b * HWSZ * CC;

    // Gather phase: 4 iters x 512 threads x float4 = 8192 floats = 64x128 tile.
    // slot -> l = slot>>4 (16 c-slots per l), c0 = (slot&15)*4.
    #pragma unroll
    for (int it = 0; it < 4; ++it) {
        const int slot = it * 512 + tid;
        const int l    = slot >> 4;           // 0..127
        const int u    = slot & 15;           // c-group
        const int c0   = u << 2;              // 0,4,...,60
        f32x4 v = *reinterpret_cast<const f32x4*>(src + (size_t)sidx[l] * CC + c0);
        const int gs = (((l >> 2) ^ u) << 2) + (l & 3);   // swizzled column
        tile[c0 + 0][gs] = v.x;
        tile[c0 + 1][gs] = v.y;
        tile[c0 + 2][gs] = v.z;
        tile[c0 + 3][gs] = v.w;
    }
    __syncthreads();

    // Write phase: 4 iters; c = it*16 + tid/32, s = tid&31 -> l = 4s..4s+3.
    float* dst = out + ((size_t)b * (NP * CC) + (size_t)p * CC) * HWSZ + l0;
    #pragma unroll
    for (int it = 0; it < 4; ++it) {
        const int c = it * 16 + (tid >> 5);   // 0..63
        const int s = tid & 31;               // l-group
        const int g = (s ^ (c >> 2)) << 2;    // swizzled 16B group (contiguous)
        f32x4 v = *reinterpret_cast<const f32x4*>(&tile[c][g]);  // ds_read_b128
        __builtin_nontemporal_store(v,
            reinterpret_cast<f32x4*>(dst + (size_t)c * HWSZ + 4 * s));
    }
}

// ---------------------------------------------------------------------------
// Fallback (only if ws too small): direct gather, lanes along l, loop c.
// ---------------------------------------------------------------------------
__global__ __launch_bounds__(256) void naive_gather(const float* __restrict__ img,
                                                    const int* __restrict__ paths,
                                                    float* __restrict__ out) {
    const int l = blockIdx.x * 256 + threadIdx.x;
    const int p = blockIdx.y;
    const int b = blockIdx.z;
    int2 hw2 = reinterpret_cast<const int2*>(paths)[(size_t)p * HWSZ + l];
    const int idx = hw2.x * WW + hw2.y;
    const float* src = img + (size_t)b * CC * HWSZ;
    float* dst = out + ((size_t)b * NP + p) * (size_t)(CC * HWSZ) + l;
    #pragma unroll 4
    for (int c = 0; c < CC; ++c) {
        dst[(size_t)c * HWSZ] = src[(size_t)c * HWSZ + idx];
    }
}

extern "C" void kernel_launch(void* const* d_in, const int* in_sizes, int n_in,
                              void* d_out, int out_size, void* d_ws, size_t ws_size,
                              hipStream_t stream) {
    const float* img   = (const float*)d_in[0];
    const int*   paths = (const int*)d_in[1];
    float*       out   = (float*)d_out;

    const size_t need = (size_t)BB * HWSZ * CC * sizeof(float);  // 102.8 MB
    if (ws_size >= need) {
        float* img_t = (float*)d_ws;
        transpose_kernel<<<dim3(HWSZ / LT, BB), 256, 0, stream>>>(img, img_t);
        gather_kernel<<<dim3(HWSZ / TL, NP, BB), 512, 0, stream>>>(img_t, paths, out);
    } else {
        naive_gather<<<dim3(HWSZ / 256, NP, BB), 256, 0, stream>>>(img, paths, out);
    }
}